// Round 1
// baseline (3558.555 us; speedup 1.0000x reference)
//
#include <hip/hip_runtime.h>

#define H   128
#define NU  200000
#define NM  50000
#define NE  600000

// ---------------- encoders: h = relu(x @ W + b), K small ----------------
__global__ void encode_kernel(const float* __restrict__ x, const float* __restrict__ W,
                              const float* __restrict__ b, float* __restrict__ h,
                              int n, int K) {
    int idx = blockIdx.x * blockDim.x + threadIdx.x;
    if (idx >= n * H) return;
    int r = idx >> 7, c = idx & (H - 1);
    float acc = b[c];
    for (int k = 0; k < K; k++) acc = fmaf(x[r * K + k], W[k * H + c], acc);
    h[idx] = fmaxf(acc, 0.f);
}

// ---------------- CSR build ----------------
__global__ void count_kernel(const int* __restrict__ ei, int* cu, int* cm, int n) {
    int e = blockIdx.x * blockDim.x + threadIdx.x;
    if (e >= n) return;
    atomicAdd(&cu[ei[e]], 1);
    atomicAdd(&cm[ei[NE + e]], 1);
}

// exclusive scan of cnt[0..n) into rp[0..n], single block of 1024 threads
__global__ void scan_kernel(const int* __restrict__ cnt, int* __restrict__ rp, int n) {
    __shared__ int s[1024];
    int t = threadIdx.x;
    int chunk = (n + 1023) / 1024;
    int beg = t * chunk;
    int end = beg + chunk; if (end > n) end = n; if (beg > n) beg = n;
    int sum = 0;
    for (int i = beg; i < end; i++) sum += cnt[i];
    s[t] = sum;
    __syncthreads();
    for (int off = 1; off < 1024; off <<= 1) {
        int v = (t >= off) ? s[t - off] : 0;
        __syncthreads();
        s[t] += v;
        __syncthreads();
    }
    int run = s[t] - sum;  // exclusive prefix
    for (int i = beg; i < end; i++) { rp[i] = run; run += cnt[i]; }
    if (t == 1023) rp[n] = s[1023];
}

__global__ void fill_kernel(const int* __restrict__ ei, const int* __restrict__ rpu,
                            const int* __restrict__ rpm, int* cu, int* cm,
                            int* __restrict__ eu, int* __restrict__ em, int n) {
    int e = blockIdx.x * blockDim.x + threadIdx.x;
    if (e >= n) return;
    int s = ei[e], d = ei[NE + e];
    eu[rpu[s] + atomicAdd(&cu[s], 1)] = e;
    em[rpm[d] + atomicAdd(&cm[d], 1)] = e;
}

// ---------------- fused SAGE conv: out = relu(mean_nb @ wl + bl + self @ wr) ----------------
__global__ void __launch_bounds__(128)
conv_kernel(const float* __restrict__ h_nb, const float* __restrict__ h_self,
            const int* __restrict__ rp, const int* __restrict__ eids,
            const int* __restrict__ nb_of_edge,
            const float* __restrict__ wl, const float* __restrict__ wr,
            const float* __restrict__ bl, float* __restrict__ out, int n) {
    int m = blockIdx.x;
    if (m >= n) return;
    int c = threadIdx.x;  // 0..127
    __shared__ float a0[H], a1[H];
    int beg = rp[m], end = rp[m + 1];
    float acc = 0.f;
    for (int j = beg; j < end; j++) {
        int nb = nb_of_edge[eids[j]];
        acc += h_nb[nb * H + c];
    }
    int deg = end - beg;
    float inv = 1.0f / (float)(deg > 1 ? deg : 1);
    a0[c] = acc * inv;
    a1[c] = h_self[m * H + c];
    __syncthreads();
    float o = bl[c];
#pragma unroll 8
    for (int k = 0; k < H; k++) o = fmaf(a0[k], wl[k * H + c], o);
#pragma unroll 8
    for (int k = 0; k < H; k++) o = fmaf(a1[k], wr[k * H + c], o);
    out[m * H + c] = fmaxf(o, 0.f);
}

// ---------------- final per-edge MLP ----------------
// feats = [h_u[src] | h_m[dst] | relu(ea @ ew + eb)]  (384)
// out[e] = relu(feats @ c1w + c1b) . c2w + c2b
// 16 edges per block, 128 threads, each thread: 4 edges x 4 cols register tile.
__global__ void __launch_bounds__(128)
edge_mlp_kernel(const float* __restrict__ h_u, const float* __restrict__ h_m,
                const float* __restrict__ ea, const float* __restrict__ ew,
                const float* __restrict__ ebias,
                const float* __restrict__ c1w, const float* __restrict__ c1b,
                const float* __restrict__ c2w, const float* __restrict__ c2b,
                const int* __restrict__ ei, float* __restrict__ out) {
    const int ET = 16;
    int e0 = blockIdx.x * ET;
    int t = threadIdx.x;
    __shared__ float f[ET][3 * H];
    __shared__ int se[ET], de[ET];
    if (t < ET) {
        se[t] = ei[e0 + t];
        de[t] = ei[NE + e0 + t];
    }
    __syncthreads();
    int c = t;  // 0..127
#pragma unroll 4
    for (int ee = 0; ee < ET; ee++) {
        f[ee][c]         = h_u[se[ee] * H + c];
        f[ee][H + c]     = h_m[de[ee] * H + c];
        float a0v = ea[(e0 + ee) * 2], a1v = ea[(e0 + ee) * 2 + 1];
        f[ee][2 * H + c] = fmaxf(fmaf(a0v, ew[c], fmaf(a1v, ew[H + c], ebias[c])), 0.f);
    }
    __syncthreads();

    int cg = t & 31;   // column group: cols 4*cg .. 4*cg+3
    int eg = t >> 5;   // edge group:  edges 4*eg .. 4*eg+3
    float acc[4][4];
#pragma unroll
    for (int i = 0; i < 4; i++)
#pragma unroll
        for (int j = 0; j < 4; j++) acc[i][j] = c1b[cg * 4 + j];

#pragma unroll 4
    for (int k = 0; k < 3 * H; k++) {
        float4 w = *reinterpret_cast<const float4*>(&c1w[k * H + cg * 4]);
#pragma unroll
        for (int i = 0; i < 4; i++) {
            float a = f[eg * 4 + i][k];
            acc[i][0] = fmaf(a, w.x, acc[i][0]);
            acc[i][1] = fmaf(a, w.y, acc[i][1]);
            acc[i][2] = fmaf(a, w.z, acc[i][2]);
            acc[i][3] = fmaf(a, w.w, acc[i][3]);
        }
    }

    float c2l[4];
#pragma unroll
    for (int j = 0; j < 4; j++) c2l[j] = c2w[cg * 4 + j];
    float bias2 = c2b[0];
#pragma unroll
    for (int i = 0; i < 4; i++) {
        float p = 0.f;
#pragma unroll
        for (int j = 0; j < 4; j++) p += fmaxf(acc[i][j], 0.f) * c2l[j];
        // reduce over the 32 lanes of this edge-group (xor masks < 32 stay in-half)
#pragma unroll
        for (int off = 16; off >= 1; off >>= 1) p += __shfl_xor(p, off, 64);
        if (cg == 0) out[e0 + eg * 4 + i] = p + bias2;
    }
}

extern "C" void kernel_launch(void* const* d_in, const int* in_sizes, int n_in,
                              void* d_out, int out_size, void* d_ws, size_t ws_size,
                              hipStream_t stream) {
    const float* user_x     = (const float*)d_in[0];
    const float* merchant_x = (const float*)d_in[1];
    const float* edge_attr  = (const float*)d_in[2];
    const float* user_w     = (const float*)d_in[3];
    const float* user_b     = (const float*)d_in[4];
    const float* merch_w    = (const float*)d_in[5];
    const float* merch_b    = (const float*)d_in[6];
    const float* edge_w     = (const float*)d_in[7];
    const float* edge_b     = (const float*)d_in[8];
    const float* u2m_wl     = (const float*)d_in[9];
    const float* u2m_bl     = (const float*)d_in[10];
    const float* u2m_wr     = (const float*)d_in[11];
    const float* m2u_wl     = (const float*)d_in[12];
    const float* m2u_bl     = (const float*)d_in[13];
    const float* m2u_wr     = (const float*)d_in[14];
    const float* c1w        = (const float*)d_in[15];
    const float* c1b        = (const float*)d_in[16];
    const float* c2w        = (const float*)d_in[17];
    const float* c2b        = (const float*)d_in[18];
    const int*   ei         = (const int*)d_in[19];
    float* out = (float*)d_out;

    float* ws  = (float*)d_ws;
    float* hu  = ws;
    float* hm  = hu + (size_t)NU * H;
    float* hu2 = hm + (size_t)NM * H;
    float* hm2 = hu2 + (size_t)NU * H;
    int* rpu = (int*)(hm2 + (size_t)NM * H);
    int* rpm = rpu + (NU + 1);
    int* cu  = rpm + (NM + 1);
    int* cm  = cu + NU;
    int* eu  = cm + NM;
    int* em  = eu + NE;

    // zero degree counters (cu,cm contiguous)
    hipMemsetAsync(cu, 0, (size_t)(NU + NM) * sizeof(int), stream);

    encode_kernel<<<(NU * H + 255) / 256, 256, 0, stream>>>(user_x, user_w, user_b, hu, NU, 3);
    encode_kernel<<<(NM * H + 255) / 256, 256, 0, stream>>>(merchant_x, merch_w, merch_b, hm, NM, 2);

    count_kernel<<<(NE + 255) / 256, 256, 0, stream>>>(ei, cu, cm, NE);
    scan_kernel<<<1, 1024, 0, stream>>>(cu, rpu, NU);
    scan_kernel<<<1, 1024, 0, stream>>>(cm, rpm, NM);
    hipMemsetAsync(cu, 0, (size_t)(NU + NM) * sizeof(int), stream);
    fill_kernel<<<(NE + 255) / 256, 256, 0, stream>>>(ei, rpu, rpm, cu, cm, eu, em, NE);

    const float* pu = hu; const float* pm = hm;
    float* qu = hu2; float* qm = hm2;
    for (int l = 0; l < 2; l++) {
        // user -> merchant: aggregate users (neighbors = src) per merchant
        conv_kernel<<<NM, 128, 0, stream>>>(pu, pm, rpm, em, ei,
                                            u2m_wl + (size_t)l * H * H, u2m_wr + (size_t)l * H * H,
                                            u2m_bl + (size_t)l * H, qm, NM);
        // merchant -> user: aggregate merchants (neighbors = dst) per user
        conv_kernel<<<NU, 128, 0, stream>>>(pm, pu, rpu, eu, ei + NE,
                                            m2u_wl + (size_t)l * H * H, m2u_wr + (size_t)l * H * H,
                                            m2u_bl + (size_t)l * H, qu, NU);
        const float* tu = pu; pu = qu; qu = (float*)tu;
        const float* tm = pm; pm = qm; qm = (float*)tm;
    }

    edge_mlp_kernel<<<NE / 16, 128, 0, stream>>>(pu, pm, edge_attr, edge_w, edge_b,
                                                 c1w, c1b, c2w, c2b, ei, out);
}

// Round 2
// 2584.722 us; speedup vs baseline: 1.3768x; 1.3768x over previous
//
#include <hip/hip_runtime.h>

#define H   128
#define NU  200000
#define NM  50000
#define NE  600000

// ---------------- encoders: h = relu(x @ W + b), K small ----------------
__global__ void encode_kernel(const float* __restrict__ x, const float* __restrict__ W,
                              const float* __restrict__ b, float* __restrict__ h,
                              int n, int K) {
    int idx = blockIdx.x * blockDim.x + threadIdx.x;
    if (idx >= n * H) return;
    int r = idx >> 7, c = idx & (H - 1);
    float acc = b[c];
    for (int k = 0; k < K; k++) acc = fmaf(x[r * K + k], W[k * H + c], acc);
    h[idx] = fmaxf(acc, 0.f);
}

// ---------------- CSR build ----------------
__global__ void count_kernel(const int* __restrict__ ei, int* cu, int* cm, int n) {
    int e = blockIdx.x * blockDim.x + threadIdx.x;
    if (e >= n) return;
    atomicAdd(&cu[ei[e]], 1);
    atomicAdd(&cm[ei[NE + e]], 1);
}

// exclusive scan of cnt[0..n) into rp[0..n], single block of 1024 threads
__global__ void scan_kernel(const int* __restrict__ cnt, int* __restrict__ rp, int n) {
    __shared__ int s[1024];
    int t = threadIdx.x;
    int chunk = (n + 1023) / 1024;
    int beg = t * chunk;
    int end = beg + chunk; if (end > n) end = n; if (beg > n) beg = n;
    int sum = 0;
    for (int i = beg; i < end; i++) sum += cnt[i];
    s[t] = sum;
    __syncthreads();
    for (int off = 1; off < 1024; off <<= 1) {
        int v = (t >= off) ? s[t - off] : 0;
        __syncthreads();
        s[t] += v;
        __syncthreads();
    }
    int run = s[t] - sum;  // exclusive prefix
    for (int i = beg; i < end; i++) { rp[i] = run; run += cnt[i]; }
    if (t == 1023) rp[n] = s[1023];
}

// stores the OTHER endpoint directly (neighbor id), not the edge id
__global__ void fill_kernel(const int* __restrict__ ei, const int* __restrict__ rpu,
                            const int* __restrict__ rpm, int* cu, int* cm,
                            int* __restrict__ eu, int* __restrict__ em, int n) {
    int e = blockIdx.x * blockDim.x + threadIdx.x;
    if (e >= n) return;
    int s = ei[e], d = ei[NE + e];
    eu[rpu[s] + atomicAdd(&cu[s], 1)] = d;  // user's neighbor = merchant
    em[rpm[d] + atomicAdd(&cm[d], 1)] = s;  // merchant's neighbor = user
}

// ---------------- segment mean: agg[m] = mean over neighbors of h_nb ----------------
__global__ void __launch_bounds__(128)
agg_kernel(const float* __restrict__ h_nb, const int* __restrict__ rp,
           const int* __restrict__ nbl, float* __restrict__ agg, int n) {
    int m = blockIdx.x;
    if (m >= n) return;
    int c = threadIdx.x;
    int beg = rp[m], end = rp[m + 1];
    float acc = 0.f;
    for (int j = beg; j < end; j++) acc += h_nb[(size_t)nbl[j] * H + c];
    int deg = end - beg;
    agg[(size_t)m * H + c] = acc / (float)(deg > 1 ? deg : 1);
}

// ---------------- register-tiled GEMM helper ----------------
// acc[4][8] += f[eg*4+i][koff + k] * w[k*H + c0 + j]  over k in [0,128)
template <int STRIDE>
__device__ __forceinline__ void gemm_128(const float (*f)[STRIDE], const float* __restrict__ w,
                                         int eg, int c0, int koff, float acc[4][8]) {
#pragma unroll 2
    for (int kb = 0; kb < 128; kb += 4) {
        float4 a[4];
#pragma unroll
        for (int i = 0; i < 4; i++) a[i] = *(const float4*)&f[eg * 4 + i][koff + kb];
#pragma unroll
        for (int kk = 0; kk < 4; kk++) {
            float4 w0 = *(const float4*)&w[(kb + kk) * H + c0];
            float4 w1 = *(const float4*)&w[(kb + kk) * H + c0 + 4];
#pragma unroll
            for (int i = 0; i < 4; i++) {
                float av = ((const float*)&a[i])[kk];
                acc[i][0] = fmaf(av, w0.x, acc[i][0]);
                acc[i][1] = fmaf(av, w0.y, acc[i][1]);
                acc[i][2] = fmaf(av, w0.z, acc[i][2]);
                acc[i][3] = fmaf(av, w0.w, acc[i][3]);
                acc[i][4] = fmaf(av, w1.x, acc[i][4]);
                acc[i][5] = fmaf(av, w1.y, acc[i][5]);
                acc[i][6] = fmaf(av, w1.z, acc[i][6]);
                acc[i][7] = fmaf(av, w1.w, acc[i][7]);
            }
        }
    }
}

// ---------------- conv GEMM: out = relu(agg @ wl + bl + self @ wr) ----------------
// 32 nodes x 128 cols per block, 128 threads, 4x8 register tile each.
// NOTE: `out` may alias `agg` (each block reads its rows into LDS before storing).
__global__ void __launch_bounds__(128)
conv_gemm_kernel(const float* __restrict__ agg, const float* __restrict__ self,
                 const float* __restrict__ wl, const float* __restrict__ wr,
                 const float* __restrict__ bl, float* __restrict__ out, int n) {
    const int NT = 32;
    int node0 = blockIdx.x * NT;
    int t = threadIdx.x;
    __shared__ float f[NT][260];  // [agg | self], pad to 260 (16B-aligned rows, 2-way banks)

#pragma unroll 4
    for (int p = 0; p < 16; p++) {
        int i = p * 2 + (t >> 6);
        int node = node0 + i; if (node >= n) node = n - 1;
        int cc = (t & 63) * 4;
        const float* s = (cc < 128) ? &agg[(size_t)node * H + cc]
                                    : &self[(size_t)node * H + (cc - 128)];
        *(float4*)&f[i][cc] = *(const float4*)s;
    }
    __syncthreads();

    int cg = t & 15, eg = t >> 4;
    int c0 = cg * 8;
    float4 b0 = *(const float4*)&bl[c0];
    float4 b1 = *(const float4*)&bl[c0 + 4];
    float acc[4][8];
#pragma unroll
    for (int i = 0; i < 4; i++) {
        acc[i][0] = b0.x; acc[i][1] = b0.y; acc[i][2] = b0.z; acc[i][3] = b0.w;
        acc[i][4] = b1.x; acc[i][5] = b1.y; acc[i][6] = b1.z; acc[i][7] = b1.w;
    }
    gemm_128<260>(f, wl, eg, c0, 0, acc);
    gemm_128<260>(f, wr, eg, c0, 128, acc);

#pragma unroll
    for (int i = 0; i < 4; i++) {
        int node = node0 + eg * 4 + i;
        if (node < n) {
            float4 o0, o1;
            o0.x = fmaxf(acc[i][0], 0.f); o0.y = fmaxf(acc[i][1], 0.f);
            o0.z = fmaxf(acc[i][2], 0.f); o0.w = fmaxf(acc[i][3], 0.f);
            o1.x = fmaxf(acc[i][4], 0.f); o1.y = fmaxf(acc[i][5], 0.f);
            o1.z = fmaxf(acc[i][6], 0.f); o1.w = fmaxf(acc[i][7], 0.f);
            *(float4*)&out[(size_t)node * H + c0] = o0;
            *(float4*)&out[(size_t)node * H + c0 + 4] = o1;
        }
    }
}

// ---------------- final per-edge MLP ----------------
// feats = [h_u[src] | h_m[dst] | relu(ea @ ew + eb)]  (384)
// out[e] = relu(feats @ c1w + c1b) . c2w + c2b
// 32 edges per block, 128 threads, 4 edges x 8 cols register tile.
__global__ void __launch_bounds__(128)
edge_mlp_kernel(const float* __restrict__ h_u, const float* __restrict__ h_m,
                const float* __restrict__ ea, const float* __restrict__ ew,
                const float* __restrict__ ebias,
                const float* __restrict__ c1w, const float* __restrict__ c1b,
                const float* __restrict__ c2w, const float* __restrict__ c2b,
                const int* __restrict__ ei, float* __restrict__ out) {
    const int ET = 32;
    int e0 = blockIdx.x * ET;
    int t = threadIdx.x;
    __shared__ float f[ET][388];  // [hu | hm | e], pad to 388
    __shared__ int se[ET], de[ET];
    if (t < ET) {
        se[t] = ei[e0 + t];
        de[t] = ei[NE + e0 + t];
    }
    __syncthreads();

    // gather hu/hm parts with float4
#pragma unroll 4
    for (int p = 0; p < 16; p++) {
        int ee = p * 2 + (t >> 6);
        int cc = (t & 63) * 4;
        const float* s = (cc < 128) ? &h_u[(size_t)se[ee] * H + cc]
                                    : &h_m[(size_t)de[ee] * H + (cc - 128)];
        *(float4*)&f[ee][cc] = *(const float4*)s;
    }
    // edge encoder part
    int c = t;  // 0..127
    float ewc = ew[c], ewc2 = ew[H + c], ebc = ebias[c];
#pragma unroll 4
    for (int ee = 0; ee < ET; ee++) {
        float a0v = ea[(size_t)(e0 + ee) * 2], a1v = ea[(size_t)(e0 + ee) * 2 + 1];
        f[ee][2 * H + c] = fmaxf(fmaf(a0v, ewc, fmaf(a1v, ewc2, ebc)), 0.f);
    }
    __syncthreads();

    int cg = t & 15, eg = t >> 4;
    int c0 = cg * 8;
    float4 b0 = *(const float4*)&c1b[c0];
    float4 b1 = *(const float4*)&c1b[c0 + 4];
    float acc[4][8];
#pragma unroll
    for (int i = 0; i < 4; i++) {
        acc[i][0] = b0.x; acc[i][1] = b0.y; acc[i][2] = b0.z; acc[i][3] = b0.w;
        acc[i][4] = b1.x; acc[i][5] = b1.y; acc[i][6] = b1.z; acc[i][7] = b1.w;
    }
    gemm_128<388>(f, c1w, eg, c0, 0, acc);
    gemm_128<388>(f, c1w + 128 * H, eg, c0, 128, acc);
    gemm_128<388>(f, c1w + 256 * H, eg, c0, 256, acc);

    float4 w20 = *(const float4*)&c2w[c0];
    float4 w21 = *(const float4*)&c2w[c0 + 4];
    float bias2 = c2b[0];
#pragma unroll
    for (int i = 0; i < 4; i++) {
        float p = fmaxf(acc[i][0], 0.f) * w20.x + fmaxf(acc[i][1], 0.f) * w20.y
                + fmaxf(acc[i][2], 0.f) * w20.z + fmaxf(acc[i][3], 0.f) * w20.w
                + fmaxf(acc[i][4], 0.f) * w21.x + fmaxf(acc[i][5], 0.f) * w21.y
                + fmaxf(acc[i][6], 0.f) * w21.z + fmaxf(acc[i][7], 0.f) * w21.w;
        // reduce across the 16 lanes (cg) of this edge-group
#pragma unroll
        for (int off = 8; off >= 1; off >>= 1) p += __shfl_xor(p, off, 64);
        if (cg == 0) out[e0 + eg * 4 + i] = p + bias2;
    }
}

extern "C" void kernel_launch(void* const* d_in, const int* in_sizes, int n_in,
                              void* d_out, int out_size, void* d_ws, size_t ws_size,
                              hipStream_t stream) {
    const float* user_x     = (const float*)d_in[0];
    const float* merchant_x = (const float*)d_in[1];
    const float* edge_attr  = (const float*)d_in[2];
    const float* user_w     = (const float*)d_in[3];
    const float* user_b     = (const float*)d_in[4];
    const float* merch_w    = (const float*)d_in[5];
    const float* merch_b    = (const float*)d_in[6];
    const float* edge_w     = (const float*)d_in[7];
    const float* edge_b     = (const float*)d_in[8];
    const float* u2m_wl     = (const float*)d_in[9];
    const float* u2m_bl     = (const float*)d_in[10];
    const float* u2m_wr     = (const float*)d_in[11];
    const float* m2u_wl     = (const float*)d_in[12];
    const float* m2u_bl     = (const float*)d_in[13];
    const float* m2u_wr     = (const float*)d_in[14];
    const float* c1w        = (const float*)d_in[15];
    const float* c1b        = (const float*)d_in[16];
    const float* c2w        = (const float*)d_in[17];
    const float* c2b        = (const float*)d_in[18];
    const int*   ei         = (const int*)d_in[19];
    float* out = (float*)d_out;

    float* ws  = (float*)d_ws;
    float* hu  = ws;
    float* hm  = hu + (size_t)NU * H;
    float* hu2 = hm + (size_t)NM * H;
    float* hm2 = hu2 + (size_t)NU * H;
    int* rpu = (int*)(hm2 + (size_t)NM * H);
    int* rpm = rpu + (NU + 1);
    int* cu  = rpm + (NM + 1);
    int* cm  = cu + NU;
    int* eu  = cm + NM;
    int* em  = eu + NE;

    hipMemsetAsync(cu, 0, (size_t)(NU + NM) * sizeof(int), stream);

    encode_kernel<<<(NU * H + 255) / 256, 256, 0, stream>>>(user_x, user_w, user_b, hu, NU, 3);
    encode_kernel<<<(NM * H + 255) / 256, 256, 0, stream>>>(merchant_x, merch_w, merch_b, hm, NM, 2);

    count_kernel<<<(NE + 255) / 256, 256, 0, stream>>>(ei, cu, cm, NE);
    scan_kernel<<<1, 1024, 0, stream>>>(cu, rpu, NU);
    scan_kernel<<<1, 1024, 0, stream>>>(cm, rpm, NM);
    hipMemsetAsync(cu, 0, (size_t)(NU + NM) * sizeof(int), stream);
    fill_kernel<<<(NE + 255) / 256, 256, 0, stream>>>(ei, rpu, rpm, cu, cm, eu, em, NE);

    const float* pu = hu; const float* pm = hm;
    float* qu = hu2; float* qm = hm2;
    for (int l = 0; l < 2; l++) {
        // aggregate OLD features both directions first (agg buffers alias the outputs)
        agg_kernel<<<NM, 128, 0, stream>>>(pu, rpm, em, qm, NM);  // agg_m from users
        agg_kernel<<<NU, 128, 0, stream>>>(pm, rpu, eu, qu, NU);  // agg_u from merchants
        // user -> merchant
        conv_gemm_kernel<<<(NM + 31) / 32, 128, 0, stream>>>(
            qm, pm, u2m_wl + (size_t)l * H * H, u2m_wr + (size_t)l * H * H,
            u2m_bl + (size_t)l * H, qm, NM);
        // merchant -> user
        conv_gemm_kernel<<<(NU + 31) / 32, 128, 0, stream>>>(
            qu, pu, m2u_wl + (size_t)l * H * H, m2u_wr + (size_t)l * H * H,
            m2u_bl + (size_t)l * H, qu, NU);
        const float* tu = pu; pu = qu; qu = (float*)tu;
        const float* tm = pm; pm = qm; qm = (float*)tm;
    }

    edge_mlp_kernel<<<NE / 32, 128, 0, stream>>>(pu, pm, edge_attr, edge_w, edge_b,
                                                 c1w, c1b, c2w, c2b, ei, out);
}

// Round 3
// 1801.533 us; speedup vs baseline: 1.9753x; 1.4347x over previous
//
#include <hip/hip_runtime.h>

#define H   128
#define NU  200000
#define NM  50000
#define NE  600000

typedef __attribute__((ext_vector_type(8))) short bf16x8;
typedef __attribute__((ext_vector_type(4))) float f32x4;
typedef unsigned short ushort_t;
typedef unsigned int uint_t;

__device__ __forceinline__ ushort_t f2bf(float x) {
    uint_t b = __float_as_uint(x);
    return (ushort_t)((b + 0x7FFF + ((b >> 16) & 1)) >> 16);  // RNE
}

// ---------------- encoders: h = relu(x @ W + b), K small ----------------
__global__ void encode_kernel(const float* __restrict__ x, const float* __restrict__ W,
                              const float* __restrict__ b, float* __restrict__ h,
                              int n, int K) {
    int idx = blockIdx.x * blockDim.x + threadIdx.x;
    if (idx >= n * H) return;
    int r = idx >> 7, c = idx & (H - 1);
    float acc = b[c];
    for (int k = 0; k < K; k++) acc = fmaf(x[r * K + k], W[k * H + c], acc);
    h[idx] = fmaxf(acc, 0.f);
}

// ---------------- CSR build ----------------
__global__ void count_kernel(const int* __restrict__ ei, int* cu, int* cm, int n) {
    int e = blockIdx.x * blockDim.x + threadIdx.x;
    if (e >= n) return;
    atomicAdd(&cu[ei[e]], 1);
    atomicAdd(&cm[ei[NE + e]], 1);
}

__global__ void scan_kernel(const int* __restrict__ cnt, int* __restrict__ rp, int n) {
    __shared__ int s[1024];
    int t = threadIdx.x;
    int chunk = (n + 1023) / 1024;
    int beg = t * chunk;
    int end = beg + chunk; if (end > n) end = n; if (beg > n) beg = n;
    int sum = 0;
    for (int i = beg; i < end; i++) sum += cnt[i];
    s[t] = sum;
    __syncthreads();
    for (int off = 1; off < 1024; off <<= 1) {
        int v = (t >= off) ? s[t - off] : 0;
        __syncthreads();
        s[t] += v;
        __syncthreads();
    }
    int run = s[t] - sum;
    for (int i = beg; i < end; i++) { rp[i] = run; run += cnt[i]; }
    if (t == 1023) rp[n] = s[1023];
}

__global__ void fill_kernel(const int* __restrict__ ei, const int* __restrict__ rpu,
                            const int* __restrict__ rpm, int* cu, int* cm,
                            int* __restrict__ eu, int* __restrict__ em, int n) {
    int e = blockIdx.x * blockDim.x + threadIdx.x;
    if (e >= n) return;
    int s = ei[e], d = ei[NE + e];
    eu[rpu[s] + atomicAdd(&cu[s], 1)] = d;
    em[rpm[d] + atomicAdd(&cm[d], 1)] = s;
}

// ---------------- segment mean ----------------
__global__ void __launch_bounds__(128)
agg_kernel(const float* __restrict__ h_nb, const int* __restrict__ rp,
           const int* __restrict__ nbl, float* __restrict__ agg, int n) {
    int m = blockIdx.x;
    if (m >= n) return;
    int c = threadIdx.x;
    int beg = rp[m], end = rp[m + 1];
    float acc = 0.f;
    for (int j = beg; j < end; j++) acc += h_nb[(size_t)nbl[j] * H + c];
    int deg = end - beg;
    agg[(size_t)m * H + c] = acc / (float)(deg > 1 ? deg : 1);
}

// ---------------- fp32 register-tiled GEMM helper (convs) ----------------
template <int STRIDE>
__device__ __forceinline__ void gemm_128(const float (*f)[STRIDE], const float* __restrict__ w,
                                         int eg, int c0, int koff, float acc[4][8]) {
#pragma unroll 2
    for (int kb = 0; kb < 128; kb += 4) {
        float4 a[4];
#pragma unroll
        for (int i = 0; i < 4; i++) a[i] = *(const float4*)&f[eg * 4 + i][koff + kb];
#pragma unroll
        for (int kk = 0; kk < 4; kk++) {
            float4 w0 = *(const float4*)&w[(kb + kk) * H + c0];
            float4 w1 = *(const float4*)&w[(kb + kk) * H + c0 + 4];
#pragma unroll
            for (int i = 0; i < 4; i++) {
                float av = ((const float*)&a[i])[kk];
                acc[i][0] = fmaf(av, w0.x, acc[i][0]);
                acc[i][1] = fmaf(av, w0.y, acc[i][1]);
                acc[i][2] = fmaf(av, w0.z, acc[i][2]);
                acc[i][3] = fmaf(av, w0.w, acc[i][3]);
                acc[i][4] = fmaf(av, w1.x, acc[i][4]);
                acc[i][5] = fmaf(av, w1.y, acc[i][5]);
                acc[i][6] = fmaf(av, w1.z, acc[i][6]);
                acc[i][7] = fmaf(av, w1.w, acc[i][7]);
            }
        }
    }
}

// ---------------- conv GEMM (fp32): out = relu(agg @ wl + bl + self @ wr) ----------------
__global__ void __launch_bounds__(128)
conv_gemm_kernel(const float* __restrict__ agg, const float* __restrict__ self,
                 const float* __restrict__ wl, const float* __restrict__ wr,
                 const float* __restrict__ bl, float* __restrict__ out, int n) {
    const int NT = 32;
    int node0 = blockIdx.x * NT;
    int t = threadIdx.x;
    __shared__ float f[NT][260];

#pragma unroll 4
    for (int p = 0; p < 16; p++) {
        int i = p * 2 + (t >> 6);
        int node = node0 + i; if (node >= n) node = n - 1;
        int cc = (t & 63) * 4;
        const float* s = (cc < 128) ? &agg[(size_t)node * H + cc]
                                    : &self[(size_t)node * H + (cc - 128)];
        *(float4*)&f[i][cc] = *(const float4*)s;
    }
    __syncthreads();

    int cg = t & 15, eg = t >> 4;
    int c0 = cg * 8;
    float4 b0 = *(const float4*)&bl[c0];
    float4 b1 = *(const float4*)&bl[c0 + 4];
    float acc[4][8];
#pragma unroll
    for (int i = 0; i < 4; i++) {
        acc[i][0] = b0.x; acc[i][1] = b0.y; acc[i][2] = b0.z; acc[i][3] = b0.w;
        acc[i][4] = b1.x; acc[i][5] = b1.y; acc[i][6] = b1.z; acc[i][7] = b1.w;
    }
    gemm_128<260>(f, wl, eg, c0, 0, acc);
    gemm_128<260>(f, wr, eg, c0, 128, acc);

#pragma unroll
    for (int i = 0; i < 4; i++) {
        int node = node0 + eg * 4 + i;
        if (node < n) {
            float4 o0, o1;
            o0.x = fmaxf(acc[i][0], 0.f); o0.y = fmaxf(acc[i][1], 0.f);
            o0.z = fmaxf(acc[i][2], 0.f); o0.w = fmaxf(acc[i][3], 0.f);
            o1.x = fmaxf(acc[i][4], 0.f); o1.y = fmaxf(acc[i][5], 0.f);
            o1.z = fmaxf(acc[i][6], 0.f); o1.w = fmaxf(acc[i][7], 0.f);
            *(float4*)&out[(size_t)node * H + c0] = o0;
            *(float4*)&out[(size_t)node * H + c0 + 4] = o1;
        }
    }
}

// ---------------- c1w [384][128] f32 -> c1wT [128][384] bf16 ----------------
__global__ void convert_w_kernel(const float* __restrict__ c1w, ushort_t* __restrict__ outT) {
    int i = blockIdx.x * 256 + threadIdx.x;
    if (i >= 384 * 128) return;
    int k = i >> 7, n = i & 127;
    outT[n * 384 + k] = f2bf(c1w[i]);
}

// ---------------- edge MLP via MFMA ----------------
// feats[e] = [h_u[src] | h_m[dst] | relu(ea @ ew + eb)] (384, bf16)
// hid = relu(feats @ c1w + c1b); out[e] = hid . c2w + c2b
// 64 edges/block, 256 threads (4 waves). Wave w owns cols [32w, 32w+32):
// B-slice (24 x bf16x8 = 96 VGPR) lives in registers, loaded once.
// A in XOR-swizzled LDS (granule ^= row&7 -> 2-way bank access, free).
__global__ void __launch_bounds__(256)
edge_mlp_mfma_kernel(const float* __restrict__ h_u, const float* __restrict__ h_m,
                     const float* __restrict__ ea, const float* __restrict__ ew,
                     const float* __restrict__ ebias,
                     const ushort_t* __restrict__ c1wT, const float* __restrict__ c1b,
                     const float* __restrict__ c2w, const float* __restrict__ c2b,
                     const int* __restrict__ ei, float* __restrict__ out) {
    const int ET = 64;
    int e0 = blockIdx.x * ET;
    int t = threadIdx.x;
    int lane = t & 63, w = t >> 6;
    int l15 = lane & 15, koff = lane >> 4;

    __shared__ ushort_t As[ET * 384];   // 48 KB, XOR-swizzled 16B granules
    __shared__ float part[4 * ET];      // cross-wave layer-2 partials
    __shared__ int se[ET], de[ET];

    if (t < ET) {
        se[t] = ei[e0 + t];
        de[t] = ei[NE + e0 + t];
    }

    // ---- B slice into registers: bf_[ks][n1] = c1wT[col][ks*32 + koff*8 ..+7]
    bf16x8 bf_[12][2];
#pragma unroll
    for (int ks = 0; ks < 12; ks++)
#pragma unroll
        for (int n1 = 0; n1 < 2; n1++) {
            int col = w * 32 + n1 * 16 + l15;
            bf_[ks][n1] = *reinterpret_cast<const bf16x8*>(&c1wT[col * 384 + ks * 32 + koff * 8]);
        }

    __syncthreads();  // se/de visible

    // ---- gather features -> bf16 -> swizzled LDS. 64 rows x 48 granules(16B).
    char* Ab = (char*)As;
#pragma unroll
    for (int it = 0; it < 12; it++) {
        int lin = it * 256 + t;       // 0..3071
        int row = lin / 48;
        int g = lin - row * 48;
        float v[8];
        if (g < 32) {
            const float* s = (g < 16) ? &h_u[(size_t)se[row] * H + g * 8]
                                      : &h_m[(size_t)de[row] * H + (g - 16) * 8];
            float4 x = *(const float4*)s, y = *(const float4*)(s + 4);
            v[0] = x.x; v[1] = x.y; v[2] = x.z; v[3] = x.w;
            v[4] = y.x; v[5] = y.y; v[6] = y.z; v[7] = y.w;
        } else {
            int c = (g - 32) * 8;
            float a0 = ea[(size_t)(e0 + row) * 2], a1 = ea[(size_t)(e0 + row) * 2 + 1];
            float4 w0a = *(const float4*)&ew[c],       w0b = *(const float4*)&ew[c + 4];
            float4 w1a = *(const float4*)&ew[H + c],   w1b = *(const float4*)&ew[H + c + 4];
            float4 bba = *(const float4*)&ebias[c],    bbb = *(const float4*)&ebias[c + 4];
            v[0] = fmaxf(fmaf(a0, w0a.x, fmaf(a1, w1a.x, bba.x)), 0.f);
            v[1] = fmaxf(fmaf(a0, w0a.y, fmaf(a1, w1a.y, bba.y)), 0.f);
            v[2] = fmaxf(fmaf(a0, w0a.z, fmaf(a1, w1a.z, bba.z)), 0.f);
            v[3] = fmaxf(fmaf(a0, w0a.w, fmaf(a1, w1a.w, bba.w)), 0.f);
            v[4] = fmaxf(fmaf(a0, w0b.x, fmaf(a1, w1b.x, bbb.x)), 0.f);
            v[5] = fmaxf(fmaf(a0, w0b.y, fmaf(a1, w1b.y, bbb.y)), 0.f);
            v[6] = fmaxf(fmaf(a0, w0b.z, fmaf(a1, w1b.z, bbb.z)), 0.f);
            v[7] = fmaxf(fmaf(a0, w0b.w, fmaf(a1, w1b.w, bbb.w)), 0.f);
        }
        union { ushort_t u[8]; uint4 q; } pk;
#pragma unroll
        for (int j = 0; j < 8; j++) pk.u[j] = f2bf(v[j]);
        *(uint4*)(Ab + row * 768 + ((g ^ (row & 7)) << 4)) = pk.q;
    }
    __syncthreads();

    // ---- K-loop: 12 steps x (4 ds_read_b128 + 8 MFMA), no barriers
    int sw = l15 & 7;
    float bias0 = c1b[w * 32 + l15];
    float bias1 = c1b[w * 32 + 16 + l15];
    f32x4 acc[4][2];
#pragma unroll
    for (int rg = 0; rg < 4; rg++) {
        acc[rg][0] = (f32x4){bias0, bias0, bias0, bias0};
        acc[rg][1] = (f32x4){bias1, bias1, bias1, bias1};
    }
#pragma unroll
    for (int ks = 0; ks < 12; ks++) {
#pragma unroll
        for (int rg = 0; rg < 4; rg++) {
            int row = rg * 16 + l15;
            const bf16x8 a = *reinterpret_cast<const bf16x8*>(
                Ab + row * 768 + (((ks * 4 + koff) ^ sw) << 4));
            acc[rg][0] = __builtin_amdgcn_mfma_f32_16x16x32_bf16(a, bf_[ks][0], acc[rg][0], 0, 0, 0);
            acc[rg][1] = __builtin_amdgcn_mfma_f32_16x16x32_bf16(a, bf_[ks][1], acc[rg][1], 0, 0, 0);
        }
    }

    // ---- epilogue: relu + layer-2 dot. Lane holds rows rg*16+koff*4+reg, col w*32+n1*16+l15.
    float c2v0 = c2w[w * 32 + l15];
    float c2v1 = c2w[w * 32 + 16 + l15];
#pragma unroll
    for (int rg = 0; rg < 4; rg++) {
#pragma unroll
        for (int reg = 0; reg < 4; reg++) {
            float p = fmaxf(acc[rg][0][reg], 0.f) * c2v0 + fmaxf(acc[rg][1][reg], 0.f) * c2v1;
#pragma unroll
            for (int off = 8; off >= 1; off >>= 1) p += __shfl_xor(p, off, 64);
            if (l15 == 0) part[w * ET + rg * 16 + koff * 4 + reg] = p;
        }
    }
    __syncthreads();
    if (t < ET) {
        out[e0 + t] = part[t] + part[ET + t] + part[2 * ET + t] + part[3 * ET + t] + c2b[0];
    }
}

extern "C" void kernel_launch(void* const* d_in, const int* in_sizes, int n_in,
                              void* d_out, int out_size, void* d_ws, size_t ws_size,
                              hipStream_t stream) {
    const float* user_x     = (const float*)d_in[0];
    const float* merchant_x = (const float*)d_in[1];
    const float* edge_attr  = (const float*)d_in[2];
    const float* user_w     = (const float*)d_in[3];
    const float* user_b     = (const float*)d_in[4];
    const float* merch_w    = (const float*)d_in[5];
    const float* merch_b    = (const float*)d_in[6];
    const float* edge_w     = (const float*)d_in[7];
    const float* edge_b     = (const float*)d_in[8];
    const float* u2m_wl     = (const float*)d_in[9];
    const float* u2m_bl     = (const float*)d_in[10];
    const float* u2m_wr     = (const float*)d_in[11];
    const float* m2u_wl     = (const float*)d_in[12];
    const float* m2u_bl     = (const float*)d_in[13];
    const float* m2u_wr     = (const float*)d_in[14];
    const float* c1w        = (const float*)d_in[15];
    const float* c1b        = (const float*)d_in[16];
    const float* c2w        = (const float*)d_in[17];
    const float* c2b        = (const float*)d_in[18];
    const int*   ei         = (const int*)d_in[19];
    float* out = (float*)d_out;

    float* ws  = (float*)d_ws;
    float* hu  = ws;
    float* hm  = hu + (size_t)NU * H;
    float* hu2 = hm + (size_t)NM * H;
    float* hm2 = hu2 + (size_t)NU * H;
    int* rpu = (int*)(hm2 + (size_t)NM * H);
    int* rpm = rpu + (NU + 1);
    int* cu  = rpm + (NM + 1);
    int* cm  = cu + NU;
    int* eu  = cm + NM;
    int* em  = eu + NE;
    ushort_t* c1wT = (ushort_t*)(em + NE);   // 128*384 bf16 = 96 KB

    hipMemsetAsync(cu, 0, (size_t)(NU + NM) * sizeof(int), stream);

    encode_kernel<<<(NU * H + 255) / 256, 256, 0, stream>>>(user_x, user_w, user_b, hu, NU, 3);
    encode_kernel<<<(NM * H + 255) / 256, 256, 0, stream>>>(merchant_x, merch_w, merch_b, hm, NM, 2);
    convert_w_kernel<<<(384 * 128 + 255) / 256, 256, 0, stream>>>(c1w, c1wT);

    count_kernel<<<(NE + 255) / 256, 256, 0, stream>>>(ei, cu, cm, NE);
    scan_kernel<<<1, 1024, 0, stream>>>(cu, rpu, NU);
    scan_kernel<<<1, 1024, 0, stream>>>(cm, rpm, NM);
    hipMemsetAsync(cu, 0, (size_t)(NU + NM) * sizeof(int), stream);
    fill_kernel<<<(NE + 255) / 256, 256, 0, stream>>>(ei, rpu, rpm, cu, cm, eu, em, NE);

    const float* pu = hu; const float* pm = hm;
    float* qu = hu2; float* qm = hm2;
    for (int l = 0; l < 2; l++) {
        agg_kernel<<<NM, 128, 0, stream>>>(pu, rpm, em, qm, NM);
        agg_kernel<<<NU, 128, 0, stream>>>(pm, rpu, eu, qu, NU);
        conv_gemm_kernel<<<(NM + 31) / 32, 128, 0, stream>>>(
            qm, pm, u2m_wl + (size_t)l * H * H, u2m_wr + (size_t)l * H * H,
            u2m_bl + (size_t)l * H, qm, NM);
        conv_gemm_kernel<<<(NU + 31) / 32, 128, 0, stream>>>(
            qu, pu, m2u_wl + (size_t)l * H * H, m2u_wr + (size_t)l * H * H,
            m2u_bl + (size_t)l * H, qu, NU);
        const float* tu = pu; pu = qu; qu = (float*)tu;
        const float* tm = pm; pm = qm; qm = (float*)tm;
    }

    edge_mlp_mfma_kernel<<<NE / 64, 256, 0, stream>>>(pu, pm, edge_attr, edge_w, edge_b,
                                                      c1wT, c1b, c2w, c2b, ei, out);
}

// Round 4
// 1447.861 us; speedup vs baseline: 2.4578x; 1.2443x over previous
//
#include <hip/hip_runtime.h>

#define H   128
#define NU  200000
#define NM  50000
#define NE  600000

typedef __attribute__((ext_vector_type(8))) short bf16x8;
typedef __attribute__((ext_vector_type(4))) float f32x4;
typedef unsigned short ushort_t;
typedef unsigned int uint_t;

__device__ __forceinline__ ushort_t f2bf(float x) {
    uint_t b = __float_as_uint(x);
    return (ushort_t)((b + 0x7FFF + ((b >> 16) & 1)) >> 16);  // RNE
}

// ---------------- encoders: h = relu(x @ W + b), K small ----------------
__global__ void encode_kernel(const float* __restrict__ x, const float* __restrict__ W,
                              const float* __restrict__ b, float* __restrict__ h,
                              int n, int K) {
    int idx = blockIdx.x * blockDim.x + threadIdx.x;
    if (idx >= n * H) return;
    int r = idx >> 7, c = idx & (H - 1);
    float acc = b[c];
    for (int k = 0; k < K; k++) acc = fmaf(x[r * K + k], W[k * H + c], acc);
    h[idx] = fmaxf(acc, 0.f);
}

// ---------------- CSR build ----------------
__global__ void count_kernel(const int* __restrict__ ei, int* cu, int* cm, int n) {
    int e = blockIdx.x * blockDim.x + threadIdx.x;
    if (e >= n) return;
    atomicAdd(&cu[ei[e]], 1);
    atomicAdd(&cm[ei[NE + e]], 1);
}

// ---------- 3-phase multi-block exclusive scan (2048 elements / block) ----------
__global__ void __launch_bounds__(256)
scanA_kernel(const int* __restrict__ cnt, int* __restrict__ bsum, int n) {
    __shared__ int s[256];
    int b = blockIdx.x, t = threadIdx.x;
    int base = b * 2048 + t * 8;
    int sum = 0;
    if (base + 8 <= n) {
        int4 a = *(const int4*)&cnt[base];
        int4 c = *(const int4*)&cnt[base + 4];
        sum = a.x + a.y + a.z + a.w + c.x + c.y + c.z + c.w;
    } else {
        for (int j = 0; j < 8; j++) { int i = base + j; if (i < n) sum += cnt[i]; }
    }
    s[t] = sum;
    __syncthreads();
    for (int off = 128; off >= 1; off >>= 1) {
        if (t < off) s[t] += s[t + off];
        __syncthreads();
    }
    if (t == 0) bsum[b] = s[0];
}

__global__ void __launch_bounds__(256)
scanB_kernel(const int* __restrict__ bsum, int* __restrict__ boff, int nb,
             int* __restrict__ rp_total) {
    __shared__ int s[256];
    int t = threadIdx.x;
    int v = (t < nb) ? bsum[t] : 0;
    s[t] = v;
    __syncthreads();
    for (int off = 1; off < 256; off <<= 1) {
        int x = (t >= off) ? s[t - off] : 0;
        __syncthreads();
        s[t] += x;
        __syncthreads();
    }
    if (t < nb) boff[t] = s[t] - v;   // exclusive
    if (t == 255) rp_total[0] = s[255];  // rp[n] = total
}

__global__ void __launch_bounds__(256)
scanC_kernel(const int* __restrict__ cnt, const int* __restrict__ boff,
             int* __restrict__ rp, int n) {
    __shared__ int s[256];
    int b = blockIdx.x, t = threadIdx.x;
    int base = b * 2048 + t * 8;
    int v[8];
    int sum = 0;
    if (base + 8 <= n) {
        int4 a = *(const int4*)&cnt[base];
        int4 c = *(const int4*)&cnt[base + 4];
        v[0] = a.x; v[1] = a.y; v[2] = a.z; v[3] = a.w;
        v[4] = c.x; v[5] = c.y; v[6] = c.z; v[7] = c.w;
#pragma unroll
        for (int j = 0; j < 8; j++) sum += v[j];
    } else {
#pragma unroll
        for (int j = 0; j < 8; j++) { int i = base + j; v[j] = (i < n) ? cnt[i] : 0; sum += v[j]; }
    }
    s[t] = sum;
    __syncthreads();
    for (int off = 1; off < 256; off <<= 1) {
        int x = (t >= off) ? s[t - off] : 0;
        __syncthreads();
        s[t] += x;
        __syncthreads();
    }
    int run = boff[b] + s[t] - sum;  // exclusive prefix for this thread's first element
    if (base + 8 <= n) {
        int o[8];
#pragma unroll
        for (int j = 0; j < 8; j++) { o[j] = run; run += v[j]; }
        *(int4*)&rp[base]     = make_int4(o[0], o[1], o[2], o[3]);
        *(int4*)&rp[base + 4] = make_int4(o[4], o[5], o[6], o[7]);
    } else {
#pragma unroll
        for (int j = 0; j < 8; j++) { int i = base + j; if (i < n) rp[i] = run; run += v[j]; }
    }
}

__global__ void fill_kernel(const int* __restrict__ ei, const int* __restrict__ rpu,
                            const int* __restrict__ rpm, int* cu, int* cm,
                            int* __restrict__ eu, int* __restrict__ em, int n) {
    int e = blockIdx.x * blockDim.x + threadIdx.x;
    if (e >= n) return;
    int s = ei[e], d = ei[NE + e];
    eu[rpu[s] + atomicAdd(&cu[s], 1)] = d;
    em[rpm[d] + atomicAdd(&cm[d], 1)] = s;
}

// ---------------- segment mean ----------------
__global__ void __launch_bounds__(128)
agg_kernel(const float* __restrict__ h_nb, const int* __restrict__ rp,
           const int* __restrict__ nbl, float* __restrict__ agg, int n) {
    int m = blockIdx.x;
    if (m >= n) return;
    int c = threadIdx.x;
    int beg = rp[m], end = rp[m + 1];
    float acc = 0.f;
    for (int j = beg; j < end; j++) acc += h_nb[(size_t)nbl[j] * H + c];
    int deg = end - beg;
    agg[(size_t)m * H + c] = acc / (float)(deg > 1 ? deg : 1);
}

// ---------------- fp32 register-tiled GEMM helper (convs) ----------------
template <int STRIDE>
__device__ __forceinline__ void gemm_128(const float (*f)[STRIDE], const float* __restrict__ w,
                                         int eg, int c0, int koff, float acc[4][8]) {
#pragma unroll 2
    for (int kb = 0; kb < 128; kb += 4) {
        float4 a[4];
#pragma unroll
        for (int i = 0; i < 4; i++) a[i] = *(const float4*)&f[eg * 4 + i][koff + kb];
#pragma unroll
        for (int kk = 0; kk < 4; kk++) {
            float4 w0 = *(const float4*)&w[(kb + kk) * H + c0];
            float4 w1 = *(const float4*)&w[(kb + kk) * H + c0 + 4];
#pragma unroll
            for (int i = 0; i < 4; i++) {
                float av = ((const float*)&a[i])[kk];
                acc[i][0] = fmaf(av, w0.x, acc[i][0]);
                acc[i][1] = fmaf(av, w0.y, acc[i][1]);
                acc[i][2] = fmaf(av, w0.z, acc[i][2]);
                acc[i][3] = fmaf(av, w0.w, acc[i][3]);
                acc[i][4] = fmaf(av, w1.x, acc[i][4]);
                acc[i][5] = fmaf(av, w1.y, acc[i][5]);
                acc[i][6] = fmaf(av, w1.z, acc[i][6]);
                acc[i][7] = fmaf(av, w1.w, acc[i][7]);
            }
        }
    }
}

// ---------------- conv GEMM (fp32): out = relu(agg @ wl + bl + self @ wr) ----------------
__global__ void __launch_bounds__(128)
conv_gemm_kernel(const float* __restrict__ agg, const float* __restrict__ self,
                 const float* __restrict__ wl, const float* __restrict__ wr,
                 const float* __restrict__ bl, float* __restrict__ out, int n) {
    const int NT = 32;
    int node0 = blockIdx.x * NT;
    int t = threadIdx.x;
    __shared__ float f[NT][260];

#pragma unroll 4
    for (int p = 0; p < 16; p++) {
        int i = p * 2 + (t >> 6);
        int node = node0 + i; if (node >= n) node = n - 1;
        int cc = (t & 63) * 4;
        const float* s = (cc < 128) ? &agg[(size_t)node * H + cc]
                                    : &self[(size_t)node * H + (cc - 128)];
        *(float4*)&f[i][cc] = *(const float4*)s;
    }
    __syncthreads();

    int cg = t & 15, eg = t >> 4;
    int c0 = cg * 8;
    float4 b0 = *(const float4*)&bl[c0];
    float4 b1 = *(const float4*)&bl[c0 + 4];
    float acc[4][8];
#pragma unroll
    for (int i = 0; i < 4; i++) {
        acc[i][0] = b0.x; acc[i][1] = b0.y; acc[i][2] = b0.z; acc[i][3] = b0.w;
        acc[i][4] = b1.x; acc[i][5] = b1.y; acc[i][6] = b1.z; acc[i][7] = b1.w;
    }
    gemm_128<260>(f, wl, eg, c0, 0, acc);
    gemm_128<260>(f, wr, eg, c0, 128, acc);

#pragma unroll
    for (int i = 0; i < 4; i++) {
        int node = node0 + eg * 4 + i;
        if (node < n) {
            float4 o0, o1;
            o0.x = fmaxf(acc[i][0], 0.f); o0.y = fmaxf(acc[i][1], 0.f);
            o0.z = fmaxf(acc[i][2], 0.f); o0.w = fmaxf(acc[i][3], 0.f);
            o1.x = fmaxf(acc[i][4], 0.f); o1.y = fmaxf(acc[i][5], 0.f);
            o1.z = fmaxf(acc[i][6], 0.f); o1.w = fmaxf(acc[i][7], 0.f);
            *(float4*)&out[(size_t)node * H + c0] = o0;
            *(float4*)&out[(size_t)node * H + c0 + 4] = o1;
        }
    }
}

// ---------------- c1w [384][128] f32 -> c1wT [128][384] bf16 ----------------
__global__ void convert_w_kernel(const float* __restrict__ c1w, ushort_t* __restrict__ outT) {
    int i = blockIdx.x * 256 + threadIdx.x;
    if (i >= 384 * 128) return;
    int k = i >> 7, n = i & 127;
    outT[n * 384 + k] = f2bf(c1w[i]);
}

// ---------------- edge MLP via MFMA ----------------
__global__ void __launch_bounds__(256)
edge_mlp_mfma_kernel(const float* __restrict__ h_u, const float* __restrict__ h_m,
                     const float* __restrict__ ea, const float* __restrict__ ew,
                     const float* __restrict__ ebias,
                     const ushort_t* __restrict__ c1wT, const float* __restrict__ c1b,
                     const float* __restrict__ c2w, const float* __restrict__ c2b,
                     const int* __restrict__ ei, float* __restrict__ out) {
    const int ET = 64;
    int e0 = blockIdx.x * ET;
    int t = threadIdx.x;
    int lane = t & 63, w = t >> 6;
    int l15 = lane & 15, koff = lane >> 4;

    __shared__ ushort_t As[ET * 384];   // 48 KB, XOR-swizzled 16B granules
    __shared__ float part[4 * ET];
    __shared__ int se[ET], de[ET];

    if (t < ET) {
        se[t] = ei[e0 + t];
        de[t] = ei[NE + e0 + t];
    }

    bf16x8 bf_[12][2];
#pragma unroll
    for (int ks = 0; ks < 12; ks++)
#pragma unroll
        for (int n1 = 0; n1 < 2; n1++) {
            int col = w * 32 + n1 * 16 + l15;
            bf_[ks][n1] = *reinterpret_cast<const bf16x8*>(&c1wT[col * 384 + ks * 32 + koff * 8]);
        }

    __syncthreads();

    char* Ab = (char*)As;
#pragma unroll
    for (int it = 0; it < 12; it++) {
        int lin = it * 256 + t;
        int row = lin / 48;
        int g = lin - row * 48;
        float v[8];
        if (g < 32) {
            const float* s = (g < 16) ? &h_u[(size_t)se[row] * H + g * 8]
                                      : &h_m[(size_t)de[row] * H + (g - 16) * 8];
            float4 x = *(const float4*)s, y = *(const float4*)(s + 4);
            v[0] = x.x; v[1] = x.y; v[2] = x.z; v[3] = x.w;
            v[4] = y.x; v[5] = y.y; v[6] = y.z; v[7] = y.w;
        } else {
            int c = (g - 32) * 8;
            float a0 = ea[(size_t)(e0 + row) * 2], a1 = ea[(size_t)(e0 + row) * 2 + 1];
            float4 w0a = *(const float4*)&ew[c],       w0b = *(const float4*)&ew[c + 4];
            float4 w1a = *(const float4*)&ew[H + c],   w1b = *(const float4*)&ew[H + c + 4];
            float4 bba = *(const float4*)&ebias[c],    bbb = *(const float4*)&ebias[c + 4];
            v[0] = fmaxf(fmaf(a0, w0a.x, fmaf(a1, w1a.x, bba.x)), 0.f);
            v[1] = fmaxf(fmaf(a0, w0a.y, fmaf(a1, w1a.y, bba.y)), 0.f);
            v[2] = fmaxf(fmaf(a0, w0a.z, fmaf(a1, w1a.z, bba.z)), 0.f);
            v[3] = fmaxf(fmaf(a0, w0a.w, fmaf(a1, w1a.w, bba.w)), 0.f);
            v[4] = fmaxf(fmaf(a0, w0b.x, fmaf(a1, w1b.x, bbb.x)), 0.f);
            v[5] = fmaxf(fmaf(a0, w0b.y, fmaf(a1, w1b.y, bbb.y)), 0.f);
            v[6] = fmaxf(fmaf(a0, w0b.z, fmaf(a1, w1b.z, bbb.z)), 0.f);
            v[7] = fmaxf(fmaf(a0, w0b.w, fmaf(a1, w1b.w, bbb.w)), 0.f);
        }
        union { ushort_t u[8]; uint4 q; } pk;
#pragma unroll
        for (int j = 0; j < 8; j++) pk.u[j] = f2bf(v[j]);
        *(uint4*)(Ab + row * 768 + ((g ^ (row & 7)) << 4)) = pk.q;
    }
    __syncthreads();

    int sw = l15 & 7;
    float bias0 = c1b[w * 32 + l15];
    float bias1 = c1b[w * 32 + 16 + l15];
    f32x4 acc[4][2];
#pragma unroll
    for (int rg = 0; rg < 4; rg++) {
        acc[rg][0] = (f32x4){bias0, bias0, bias0, bias0};
        acc[rg][1] = (f32x4){bias1, bias1, bias1, bias1};
    }
#pragma unroll
    for (int ks = 0; ks < 12; ks++) {
#pragma unroll
        for (int rg = 0; rg < 4; rg++) {
            int row = rg * 16 + l15;
            const bf16x8 a = *reinterpret_cast<const bf16x8*>(
                Ab + row * 768 + (((ks * 4 + koff) ^ sw) << 4));
            acc[rg][0] = __builtin_amdgcn_mfma_f32_16x16x32_bf16(a, bf_[ks][0], acc[rg][0], 0, 0, 0);
            acc[rg][1] = __builtin_amdgcn_mfma_f32_16x16x32_bf16(a, bf_[ks][1], acc[rg][1], 0, 0, 0);
        }
    }

    float c2v0 = c2w[w * 32 + l15];
    float c2v1 = c2w[w * 32 + 16 + l15];
#pragma unroll
    for (int rg = 0; rg < 4; rg++) {
#pragma unroll
        for (int reg = 0; reg < 4; reg++) {
            float p = fmaxf(acc[rg][0][reg], 0.f) * c2v0 + fmaxf(acc[rg][1][reg], 0.f) * c2v1;
#pragma unroll
            for (int off = 8; off >= 1; off >>= 1) p += __shfl_xor(p, off, 64);
            if (l15 == 0) part[w * ET + rg * 16 + koff * 4 + reg] = p;
        }
    }
    __syncthreads();
    if (t < ET) {
        out[e0 + t] = part[t] + part[ET + t] + part[2 * ET + t] + part[3 * ET + t] + c2b[0];
    }
}

extern "C" void kernel_launch(void* const* d_in, const int* in_sizes, int n_in,
                              void* d_out, int out_size, void* d_ws, size_t ws_size,
                              hipStream_t stream) {
    const float* user_x     = (const float*)d_in[0];
    const float* merchant_x = (const float*)d_in[1];
    const float* edge_attr  = (const float*)d_in[2];
    const float* user_w     = (const float*)d_in[3];
    const float* user_b     = (const float*)d_in[4];
    const float* merch_w    = (const float*)d_in[5];
    const float* merch_b    = (const float*)d_in[6];
    const float* edge_w     = (const float*)d_in[7];
    const float* edge_b     = (const float*)d_in[8];
    const float* u2m_wl     = (const float*)d_in[9];
    const float* u2m_bl     = (const float*)d_in[10];
    const float* u2m_wr     = (const float*)d_in[11];
    const float* m2u_wl     = (const float*)d_in[12];
    const float* m2u_bl     = (const float*)d_in[13];
    const float* m2u_wr     = (const float*)d_in[14];
    const float* c1w        = (const float*)d_in[15];
    const float* c1b        = (const float*)d_in[16];
    const float* c2w        = (const float*)d_in[17];
    const float* c2b        = (const float*)d_in[18];
    const int*   ei         = (const int*)d_in[19];
    float* out = (float*)d_out;

    float* ws  = (float*)d_ws;
    float* hu  = ws;
    float* hm  = hu + (size_t)NU * H;
    float* hu2 = hm + (size_t)NM * H;
    float* hm2 = hu2 + (size_t)NU * H;
    int* rpu = (int*)(hm2 + (size_t)NM * H);
    int* rpm = rpu + (NU + 1);
    int* cu  = rpm + (NM + 1);
    int* cm  = cu + NU;
    int* eu  = cm + NM;
    int* em  = eu + NE;
    ushort_t* c1wT = (ushort_t*)(em + NE);   // 128*384 bf16 = 96 KB
    int* bsum_u = (int*)(c1wT + 128 * 384);
    int* boff_u = bsum_u + 128;
    int* bsum_m = boff_u + 128;
    int* boff_m = bsum_m + 128;

    const int NBU = (NU + 2047) / 2048;  // 98
    const int NBM = (NM + 2047) / 2048;  // 25

    hipMemsetAsync(cu, 0, (size_t)(NU + NM) * sizeof(int), stream);

    encode_kernel<<<(NU * H + 255) / 256, 256, 0, stream>>>(user_x, user_w, user_b, hu, NU, 3);
    encode_kernel<<<(NM * H + 255) / 256, 256, 0, stream>>>(merchant_x, merch_w, merch_b, hm, NM, 2);
    convert_w_kernel<<<(384 * 128 + 255) / 256, 256, 0, stream>>>(c1w, c1wT);

    count_kernel<<<(NE + 255) / 256, 256, 0, stream>>>(ei, cu, cm, NE);
    scanA_kernel<<<NBU, 256, 0, stream>>>(cu, bsum_u, NU);
    scanB_kernel<<<1, 256, 0, stream>>>(bsum_u, boff_u, NBU, rpu + NU);
    scanC_kernel<<<NBU, 256, 0, stream>>>(cu, boff_u, rpu, NU);
    scanA_kernel<<<NBM, 256, 0, stream>>>(cm, bsum_m, NM);
    scanB_kernel<<<1, 256, 0, stream>>>(bsum_m, boff_m, NBM, rpm + NM);
    scanC_kernel<<<NBM, 256, 0, stream>>>(cm, boff_m, rpm, NM);
    hipMemsetAsync(cu, 0, (size_t)(NU + NM) * sizeof(int), stream);
    fill_kernel<<<(NE + 255) / 256, 256, 0, stream>>>(ei, rpu, rpm, cu, cm, eu, em, NE);

    const float* pu = hu; const float* pm = hm;
    float* qu = hu2; float* qm = hm2;
    for (int l = 0; l < 2; l++) {
        agg_kernel<<<NM, 128, 0, stream>>>(pu, rpm, em, qm, NM);
        agg_kernel<<<NU, 128, 0, stream>>>(pm, rpu, eu, qu, NU);
        conv_gemm_kernel<<<(NM + 31) / 32, 128, 0, stream>>>(
            qm, pm, u2m_wl + (size_t)l * H * H, u2m_wr + (size_t)l * H * H,
            u2m_bl + (size_t)l * H, qm, NM);
        conv_gemm_kernel<<<(NU + 31) / 32, 128, 0, stream>>>(
            qu, pu, m2u_wl + (size_t)l * H * H, m2u_wr + (size_t)l * H * H,
            m2u_bl + (size_t)l * H, qu, NU);
        const float* tu = pu; pu = qu; qu = (float*)tu;
        const float* tm = pm; pm = qm; qm = (float*)tm;
    }

    edge_mlp_mfma_kernel<<<NE / 64, 256, 0, stream>>>(pu, pm, edge_attr, edge_w, edge_b,
                                                      c1wT, c1b, c2w, c2b, ei, out);
}

// Round 5
// 854.862 us; speedup vs baseline: 4.1627x; 1.6937x over previous
//
#include <hip/hip_runtime.h>

#define H   128
#define NU  200000
#define NM  50000
#define NE  600000

typedef __attribute__((ext_vector_type(8))) short bf16x8;
typedef __attribute__((ext_vector_type(4))) float f32x4;
typedef unsigned short ushort_t;
typedef unsigned int uint_t;

__device__ __forceinline__ ushort_t f2bf(float x) {
    uint_t b = __float_as_uint(x);
    return (ushort_t)((b + 0x7FFF + ((b >> 16) & 1)) >> 16);  // RNE
}

// ---------------- encoders: h = bf16(relu(x @ W + b)), K small ----------------
__global__ void __launch_bounds__(256)
encode_bf16_kernel(const float* __restrict__ x, const float* __restrict__ W,
                   const float* __restrict__ b, ushort_t* __restrict__ h,
                   int n, int K) {
    int idx = blockIdx.x * 256 + threadIdx.x;
    if (idx >= n * 16) return;
    int r = idx >> 4, c0 = (idx & 15) * 8;
    float4 ba = *(const float4*)&b[c0], bb = *(const float4*)&b[c0 + 4];
    float acc[8] = {ba.x, ba.y, ba.z, ba.w, bb.x, bb.y, bb.z, bb.w};
    for (int k = 0; k < K; k++) {
        float xv = x[r * K + k];
        float4 wa = *(const float4*)&W[k * H + c0], wb = *(const float4*)&W[k * H + c0 + 4];
        acc[0] = fmaf(xv, wa.x, acc[0]); acc[1] = fmaf(xv, wa.y, acc[1]);
        acc[2] = fmaf(xv, wa.z, acc[2]); acc[3] = fmaf(xv, wa.w, acc[3]);
        acc[4] = fmaf(xv, wb.x, acc[4]); acc[5] = fmaf(xv, wb.y, acc[5]);
        acc[6] = fmaf(xv, wb.z, acc[6]); acc[7] = fmaf(xv, wb.w, acc[7]);
    }
    union { ushort_t u[8]; uint4 q; } pk;
#pragma unroll
    for (int j = 0; j < 8; j++) pk.u[j] = f2bf(fmaxf(acc[j], 0.f));
    *(uint4*)&h[(size_t)r * H + c0] = pk.q;
}

// ---------------- CSR build ----------------
__global__ void count_kernel(const int* __restrict__ ei, int* cu, int* cm, int n) {
    int e = blockIdx.x * blockDim.x + threadIdx.x;
    if (e >= n) return;
    atomicAdd(&cu[ei[e]], 1);
    atomicAdd(&cm[ei[NE + e]], 1);
}

// ---------- 3-phase multi-block exclusive scan (2048 elements / block) ----------
__global__ void __launch_bounds__(256)
scanA_kernel(const int* __restrict__ cnt, int* __restrict__ bsum, int n) {
    __shared__ int s[256];
    int b = blockIdx.x, t = threadIdx.x;
    int base = b * 2048 + t * 8;
    int sum = 0;
    if (base + 8 <= n) {
        int4 a = *(const int4*)&cnt[base];
        int4 c = *(const int4*)&cnt[base + 4];
        sum = a.x + a.y + a.z + a.w + c.x + c.y + c.z + c.w;
    } else {
        for (int j = 0; j < 8; j++) { int i = base + j; if (i < n) sum += cnt[i]; }
    }
    s[t] = sum;
    __syncthreads();
    for (int off = 128; off >= 1; off >>= 1) {
        if (t < off) s[t] += s[t + off];
        __syncthreads();
    }
    if (t == 0) bsum[b] = s[0];
}

__global__ void __launch_bounds__(256)
scanB_kernel(const int* __restrict__ bsum, int* __restrict__ boff, int nb,
             int* __restrict__ rp_total) {
    __shared__ int s[256];
    int t = threadIdx.x;
    int v = (t < nb) ? bsum[t] : 0;
    s[t] = v;
    __syncthreads();
    for (int off = 1; off < 256; off <<= 1) {
        int x = (t >= off) ? s[t - off] : 0;
        __syncthreads();
        s[t] += x;
        __syncthreads();
    }
    if (t < nb) boff[t] = s[t] - v;
    if (t == 255) rp_total[0] = s[255];
}

__global__ void __launch_bounds__(256)
scanC_kernel(const int* __restrict__ cnt, const int* __restrict__ boff,
             int* __restrict__ rp, int n) {
    __shared__ int s[256];
    int b = blockIdx.x, t = threadIdx.x;
    int base = b * 2048 + t * 8;
    int v[8];
    int sum = 0;
    if (base + 8 <= n) {
        int4 a = *(const int4*)&cnt[base];
        int4 c = *(const int4*)&cnt[base + 4];
        v[0] = a.x; v[1] = a.y; v[2] = a.z; v[3] = a.w;
        v[4] = c.x; v[5] = c.y; v[6] = c.z; v[7] = c.w;
#pragma unroll
        for (int j = 0; j < 8; j++) sum += v[j];
    } else {
#pragma unroll
        for (int j = 0; j < 8; j++) { int i = base + j; v[j] = (i < n) ? cnt[i] : 0; sum += v[j]; }
    }
    s[t] = sum;
    __syncthreads();
    for (int off = 1; off < 256; off <<= 1) {
        int x = (t >= off) ? s[t - off] : 0;
        __syncthreads();
        s[t] += x;
        __syncthreads();
    }
    int run = boff[b] + s[t] - sum;
    if (base + 8 <= n) {
        int o[8];
#pragma unroll
        for (int j = 0; j < 8; j++) { o[j] = run; run += v[j]; }
        *(int4*)&rp[base]     = make_int4(o[0], o[1], o[2], o[3]);
        *(int4*)&rp[base + 4] = make_int4(o[4], o[5], o[6], o[7]);
    } else {
#pragma unroll
        for (int j = 0; j < 8; j++) { int i = base + j; if (i < n) rp[i] = run; run += v[j]; }
    }
}

__global__ void fill_kernel(const int* __restrict__ ei, const int* __restrict__ rpu,
                            const int* __restrict__ rpm, int* cu, int* cm,
                            int* __restrict__ eu, int* __restrict__ em, int n) {
    int e = blockIdx.x * blockDim.x + threadIdx.x;
    if (e >= n) return;
    int s = ei[e], d = ei[NE + e];
    eu[rpu[s] + atomicAdd(&cu[s], 1)] = d;
    em[rpm[d] + atomicAdd(&cm[d], 1)] = s;
}

// ---------------- segment mean over bf16 rows (fp32 accum), 1 wave per node ----------------
__global__ void __launch_bounds__(256)
agg_bf16_kernel(const ushort_t* __restrict__ h_nb, const int* __restrict__ rp,
                const int* __restrict__ nbl, ushort_t* __restrict__ agg, int n) {
    int node = blockIdx.x * 4 + (threadIdx.x >> 6);
    if (node >= n) return;
    int lane = threadIdx.x & 63;
    int beg = rp[node], end = rp[node + 1];
    float a0 = 0.f, a1 = 0.f;
    for (int j = beg; j < end; j++) {
        uint_t v = *(const uint_t*)&h_nb[(size_t)nbl[j] * H + lane * 2];
        a0 += __uint_as_float((v & 0xffffu) << 16);
        a1 += __uint_as_float(v & 0xffff0000u);
    }
    int deg = end - beg;
    float inv = 1.0f / (float)(deg > 1 ? deg : 1);
    uint_t r = (uint_t)f2bf(a0 * inv) | ((uint_t)f2bf(a1 * inv) << 16);
    *(uint_t*)&agg[(size_t)node * H + lane * 2] = r;
}

// ---------------- weight converters ----------------
// c1w [384][128] f32 -> c1wT [128 cols][384 K] bf16
__global__ void convert_w_kernel(const float* __restrict__ c1w, ushort_t* __restrict__ outT) {
    int i = blockIdx.x * 256 + threadIdx.x;
    if (i >= 384 * 128) return;
    int k = i >> 7, n = i & 127;
    outT[n * 384 + k] = f2bf(c1w[i]);
}

// wl,wr [128][128] f32 -> wT [128 cols][256 K] bf16  (k<128: wl, k>=128: wr)
__global__ void convert_conv_w_kernel(const float* __restrict__ wl, const float* __restrict__ wr,
                                      ushort_t* __restrict__ outT) {
    int i = blockIdx.x * 256 + threadIdx.x;
    if (i >= 128 * 256) return;
    int col = i >> 8, k = i & 255;
    float v = (k < 128) ? wl[k * H + col] : wr[(k - 128) * H + col];
    outT[i] = f2bf(v);
}

// ---------------- SAGE conv via MFMA ----------------
// out = bf16(relu([agg|self] @ wT' + bl)), 64 nodes/block, 256 threads (4 waves).
// Wave w owns cols [32w,32w+32): B-slice (16 x bf16x8) in registers.
// A tile 64x256 bf16 in XOR-swizzled LDS. out may alias agg (own rows only, synced).
__global__ void __launch_bounds__(256)
conv_mfma_kernel(const ushort_t* __restrict__ agg, const ushort_t* __restrict__ self,
                 const ushort_t* __restrict__ wT, const float* __restrict__ bl,
                 ushort_t* __restrict__ out, int n) {
    const int NT = 64;
    int node0 = blockIdx.x * NT;
    int t = threadIdx.x, lane = t & 63, w = t >> 6;
    int l15 = lane & 15, koff = lane >> 4;
    __shared__ ushort_t As[NT * 256];   // 32 KB

    bf16x8 bw[8][2];
#pragma unroll
    for (int ks = 0; ks < 8; ks++)
#pragma unroll
        for (int n1 = 0; n1 < 2; n1++) {
            int col = w * 32 + n1 * 16 + l15;
            bw[ks][n1] = *reinterpret_cast<const bf16x8*>(&wT[col * 256 + ks * 32 + koff * 8]);
        }

    char* Ab = (char*)As;
#pragma unroll
    for (int it = 0; it < 8; it++) {
        int lin = it * 256 + t;
        int row = lin >> 5, g = lin & 31;
        int node = node0 + row; if (node >= n) node = n - 1;
        const ushort_t* s = (g < 16) ? &agg[(size_t)node * H + g * 8]
                                     : &self[(size_t)node * H + (g - 16) * 8];
        *(uint4*)(Ab + row * 512 + ((g ^ (row & 7)) << 4)) = *(const uint4*)s;
    }
    __syncthreads();

    int sw = l15 & 7;
    float bias0 = bl[w * 32 + l15];
    float bias1 = bl[w * 32 + 16 + l15];
    f32x4 acc[4][2];
#pragma unroll
    for (int rg = 0; rg < 4; rg++) {
        acc[rg][0] = (f32x4){bias0, bias0, bias0, bias0};
        acc[rg][1] = (f32x4){bias1, bias1, bias1, bias1};
    }
#pragma unroll
    for (int ks = 0; ks < 8; ks++) {
#pragma unroll
        for (int rg = 0; rg < 4; rg++) {
            int row = rg * 16 + l15;
            const bf16x8 a = *reinterpret_cast<const bf16x8*>(
                Ab + row * 512 + (((ks * 4 + koff) ^ sw) << 4));
            acc[rg][0] = __builtin_amdgcn_mfma_f32_16x16x32_bf16(a, bw[ks][0], acc[rg][0], 0, 0, 0);
            acc[rg][1] = __builtin_amdgcn_mfma_f32_16x16x32_bf16(a, bw[ks][1], acc[rg][1], 0, 0, 0);
        }
    }

#pragma unroll
    for (int rg = 0; rg < 4; rg++)
#pragma unroll
        for (int reg = 0; reg < 4; reg++) {
            int node = node0 + rg * 16 + koff * 4 + reg;
            if (node < n) {
                out[(size_t)node * H + w * 32 + l15]      = f2bf(fmaxf(acc[rg][0][reg], 0.f));
                out[(size_t)node * H + w * 32 + 16 + l15] = f2bf(fmaxf(acc[rg][1][reg], 0.f));
            }
        }
}

// ---------------- edge MLP via MFMA (bf16 gathers) ----------------
__global__ void __launch_bounds__(256)
edge_mlp_mfma_kernel(const ushort_t* __restrict__ h_u, const ushort_t* __restrict__ h_m,
                     const float* __restrict__ ea, const float* __restrict__ ew,
                     const float* __restrict__ ebias,
                     const ushort_t* __restrict__ c1wT, const float* __restrict__ c1b,
                     const float* __restrict__ c2w, const float* __restrict__ c2b,
                     const int* __restrict__ ei, float* __restrict__ out) {
    const int ET = 64;
    int e0 = blockIdx.x * ET;
    int t = threadIdx.x;
    int lane = t & 63, w = t >> 6;
    int l15 = lane & 15, koff = lane >> 4;

    __shared__ ushort_t As[ET * 384];   // 48 KB, XOR-swizzled 16B granules
    __shared__ float part[4 * ET];
    __shared__ int se[ET], de[ET];

    if (t < ET) {
        se[t] = ei[e0 + t];
        de[t] = ei[NE + e0 + t];
    }

    bf16x8 bf_[12][2];
#pragma unroll
    for (int ks = 0; ks < 12; ks++)
#pragma unroll
        for (int n1 = 0; n1 < 2; n1++) {
            int col = w * 32 + n1 * 16 + l15;
            bf_[ks][n1] = *reinterpret_cast<const bf16x8*>(&c1wT[col * 384 + ks * 32 + koff * 8]);
        }

    __syncthreads();

    char* Ab = (char*)As;
#pragma unroll
    for (int it = 0; it < 12; it++) {
        int lin = it * 256 + t;
        int row = lin / 48;
        int g = lin - row * 48;
        if (g < 32) {
            const ushort_t* s = (g < 16) ? &h_u[(size_t)se[row] * H + g * 8]
                                         : &h_m[(size_t)de[row] * H + (g - 16) * 8];
            *(uint4*)(Ab + row * 768 + ((g ^ (row & 7)) << 4)) = *(const uint4*)s;
        } else {
            int c = (g - 32) * 8;
            float a0 = ea[(size_t)(e0 + row) * 2], a1 = ea[(size_t)(e0 + row) * 2 + 1];
            float4 w0a = *(const float4*)&ew[c],       w0b = *(const float4*)&ew[c + 4];
            float4 w1a = *(const float4*)&ew[H + c],   w1b = *(const float4*)&ew[H + c + 4];
            float4 bba = *(const float4*)&ebias[c],    bbb = *(const float4*)&ebias[c + 4];
            float v[8];
            v[0] = fmaxf(fmaf(a0, w0a.x, fmaf(a1, w1a.x, bba.x)), 0.f);
            v[1] = fmaxf(fmaf(a0, w0a.y, fmaf(a1, w1a.y, bba.y)), 0.f);
            v[2] = fmaxf(fmaf(a0, w0a.z, fmaf(a1, w1a.z, bba.z)), 0.f);
            v[3] = fmaxf(fmaf(a0, w0a.w, fmaf(a1, w1a.w, bba.w)), 0.f);
            v[4] = fmaxf(fmaf(a0, w0b.x, fmaf(a1, w1b.x, bbb.x)), 0.f);
            v[5] = fmaxf(fmaf(a0, w0b.y, fmaf(a1, w1b.y, bbb.y)), 0.f);
            v[6] = fmaxf(fmaf(a0, w0b.z, fmaf(a1, w1b.z, bbb.z)), 0.f);
            v[7] = fmaxf(fmaf(a0, w0b.w, fmaf(a1, w1b.w, bbb.w)), 0.f);
            union { ushort_t u[8]; uint4 q; } pk;
#pragma unroll
            for (int j = 0; j < 8; j++) pk.u[j] = f2bf(v[j]);
            *(uint4*)(Ab + row * 768 + ((g ^ (row & 7)) << 4)) = pk.q;
        }
    }
    __syncthreads();

    int sw = l15 & 7;
    float bias0 = c1b[w * 32 + l15];
    float bias1 = c1b[w * 32 + 16 + l15];
    f32x4 acc[4][2];
#pragma unroll
    for (int rg = 0; rg < 4; rg++) {
        acc[rg][0] = (f32x4){bias0, bias0, bias0, bias0};
        acc[rg][1] = (f32x4){bias1, bias1, bias1, bias1};
    }
#pragma unroll
    for (int ks = 0; ks < 12; ks++) {
#pragma unroll
        for (int rg = 0; rg < 4; rg++) {
            int row = rg * 16 + l15;
            const bf16x8 a = *reinterpret_cast<const bf16x8*>(
                Ab + row * 768 + (((ks * 4 + koff) ^ sw) << 4));
            acc[rg][0] = __builtin_amdgcn_mfma_f32_16x16x32_bf16(a, bf_[ks][0], acc[rg][0], 0, 0, 0);
            acc[rg][1] = __builtin_amdgcn_mfma_f32_16x16x32_bf16(a, bf_[ks][1], acc[rg][1], 0, 0, 0);
        }
    }

    float c2v0 = c2w[w * 32 + l15];
    float c2v1 = c2w[w * 32 + 16 + l15];
#pragma unroll
    for (int rg = 0; rg < 4; rg++) {
#pragma unroll
        for (int reg = 0; reg < 4; reg++) {
            float p = fmaxf(acc[rg][0][reg], 0.f) * c2v0 + fmaxf(acc[rg][1][reg], 0.f) * c2v1;
#pragma unroll
            for (int off = 8; off >= 1; off >>= 1) p += __shfl_xor(p, off, 64);
            if (l15 == 0) part[w * ET + rg * 16 + koff * 4 + reg] = p;
        }
    }
    __syncthreads();
    if (t < ET) {
        out[e0 + t] = part[t] + part[ET + t] + part[2 * ET + t] + part[3 * ET + t] + c2b[0];
    }
}

extern "C" void kernel_launch(void* const* d_in, const int* in_sizes, int n_in,
                              void* d_out, int out_size, void* d_ws, size_t ws_size,
                              hipStream_t stream) {
    const float* user_x     = (const float*)d_in[0];
    const float* merchant_x = (const float*)d_in[1];
    const float* edge_attr  = (const float*)d_in[2];
    const float* user_w     = (const float*)d_in[3];
    const float* user_b     = (const float*)d_in[4];
    const float* merch_w    = (const float*)d_in[5];
    const float* merch_b    = (const float*)d_in[6];
    const float* edge_w     = (const float*)d_in[7];
    const float* edge_b     = (const float*)d_in[8];
    const float* u2m_wl     = (const float*)d_in[9];
    const float* u2m_bl     = (const float*)d_in[10];
    const float* u2m_wr     = (const float*)d_in[11];
    const float* m2u_wl     = (const float*)d_in[12];
    const float* m2u_bl     = (const float*)d_in[13];
    const float* m2u_wr     = (const float*)d_in[14];
    const float* c1w        = (const float*)d_in[15];
    const float* c1b        = (const float*)d_in[16];
    const float* c2w        = (const float*)d_in[17];
    const float* c2b        = (const float*)d_in[18];
    const int*   ei         = (const int*)d_in[19];
    float* out = (float*)d_out;

    // ---- workspace layout (bf16 h buffers first, 16B-aligned throughout) ----
    ushort_t* hu   = (ushort_t*)d_ws;
    ushort_t* hm   = hu  + (size_t)NU * H;
    ushort_t* hu2  = hm  + (size_t)NM * H;
    ushort_t* hm2  = hu2 + (size_t)NU * H;
    ushort_t* c1wT = hm2 + (size_t)NM * H;        // 384*128
    ushort_t* wTc  = c1wT + 384 * 128;            // 4 x 128*256 (u2m l0, u2m l1, m2u l0, m2u l1)
    int* rpu = (int*)(wTc + 4 * 128 * 256);
    int* rpm = rpu + (NU + 1);
    int* cu  = rpm + (NM + 1);
    int* cm  = cu + NU;
    int* eu  = cm + NM;
    int* em  = eu + NE;
    int* bsum_u = em + NE;
    int* boff_u = bsum_u + 128;
    int* bsum_m = boff_u + 128;
    int* boff_m = bsum_m + 128;

    const int NBU = (NU + 2047) / 2048;  // 98
    const int NBM = (NM + 2047) / 2048;  // 25

    hipMemsetAsync(cu, 0, (size_t)(NU + NM) * sizeof(int), stream);

    encode_bf16_kernel<<<(NU * 16 + 255) / 256, 256, 0, stream>>>(user_x, user_w, user_b, hu, NU, 3);
    encode_bf16_kernel<<<(NM * 16 + 255) / 256, 256, 0, stream>>>(merchant_x, merch_w, merch_b, hm, NM, 2);
    convert_w_kernel<<<(384 * 128 + 255) / 256, 256, 0, stream>>>(c1w, c1wT);
    for (int l = 0; l < 2; l++) {
        convert_conv_w_kernel<<<128, 256, 0, stream>>>(
            u2m_wl + (size_t)l * H * H, u2m_wr + (size_t)l * H * H, wTc + (size_t)l * 128 * 256);
        convert_conv_w_kernel<<<128, 256, 0, stream>>>(
            m2u_wl + (size_t)l * H * H, m2u_wr + (size_t)l * H * H, wTc + (size_t)(2 + l) * 128 * 256);
    }

    count_kernel<<<(NE + 255) / 256, 256, 0, stream>>>(ei, cu, cm, NE);
    scanA_kernel<<<NBU, 256, 0, stream>>>(cu, bsum_u, NU);
    scanB_kernel<<<1, 256, 0, stream>>>(bsum_u, boff_u, NBU, rpu + NU);
    scanC_kernel<<<NBU, 256, 0, stream>>>(cu, boff_u, rpu, NU);
    scanA_kernel<<<NBM, 256, 0, stream>>>(cm, bsum_m, NM);
    scanB_kernel<<<1, 256, 0, stream>>>(bsum_m, boff_m, NBM, rpm + NM);
    scanC_kernel<<<NBM, 256, 0, stream>>>(cm, boff_m, rpm, NM);
    hipMemsetAsync(cu, 0, (size_t)(NU + NM) * sizeof(int), stream);
    fill_kernel<<<(NE + 255) / 256, 256, 0, stream>>>(ei, rpu, rpm, cu, cm, eu, em, NE);

    const ushort_t* pu = hu; const ushort_t* pm = hm;
    ushort_t* qu = hu2; ushort_t* qm = hm2;
    for (int l = 0; l < 2; l++) {
        agg_bf16_kernel<<<(NM + 3) / 4, 256, 0, stream>>>(pu, rpm, em, qm, NM);
        agg_bf16_kernel<<<(NU + 3) / 4, 256, 0, stream>>>(pm, rpu, eu, qu, NU);
        conv_mfma_kernel<<<(NM + 63) / 64, 256, 0, stream>>>(
            qm, pm, wTc + (size_t)l * 128 * 256, u2m_bl + (size_t)l * H, qm, NM);
        conv_mfma_kernel<<<(NU + 63) / 64, 256, 0, stream>>>(
            qu, pu, wTc + (size_t)(2 + l) * 128 * 256, m2u_bl + (size_t)l * H, qu, NU);
        const ushort_t* tu = pu; pu = qu; qu = (ushort_t*)tu;
        const ushort_t* tm = pm; pm = qm; qm = (ushort_t*)tm;
    }

    edge_mlp_mfma_kernel<<<NE / 64, 256, 0, stream>>>(pu, pm, edge_attr, edge_w, edge_b,
                                                      c1wT, c1b, c2w, c2b, ei, out);
}